// Round 4
// baseline (37957.407 us; speedup 1.0000x reference)
//
#include <hip/hip_runtime.h>
#include <math.h>
#include <stdint.h>

// RHN round 6: per-WAVE synchronization -- zero barriers in the scan loop.
//  - Dataflow is wave-to-wave: wave w of (d,cg) writes state rows [16w,16w+16)
//    and the consumer wave w of stage d+1 reads exactly those rows (all cg').
//    The 4 wave-pipelines (batch-row groups of 16) are fully independent.
//  - Flags: [stage][wave][cg] ints. A wave publishes after ITS OWN
//    s_waitcnt vmcnt(0) (agent-atomic stores MALL-acked => data-before-flag
//    invariant preserved per wave). Consumer wave polls its own 64-flag line
//    (coalesced 64-lane agent load + __all) with s_sleep backoff.
//  - No __syncthreads in the loop: no WG-wide store drain, no cross-wave
//    straggler coupling, no barrier release latency.
//  - Rest identical to r5: fused two-layer beat (513 beats x 4 stages),
//    128KB LDS weights, acquire-fence + cached mirror reads, hg0 prefetch,
//    early carry loads, streamed w_in[1] at stage 0, dead-end stores
//    post-flag.

#define SEQ 512
#define NB 64
#define HID 1024
#define NH2 2048
#define NL 2
#define ND 4
#define SBUF (NB * HID)                    // 65536
#define WSLOT ((size_t)NH2 * (size_t)HID)  // 2097152 elems per slot
#define MROWS (SEQ * NB)                   // 32768

typedef _Float16 half8 __attribute__((ext_vector_type(8)));
typedef float float4v __attribute__((ext_vector_type(4)));

// ---- workspace layout (bytes) ----
#define OFF_HG0 ((size_t)10 * WSLOT * 2)                 // Wt = 40MB
#define OFF_SSEQ (OFF_HG0 + (size_t)MROWS * NH2 * 2)     // HG0 = 128MB
#define OFF_MIR (OFF_SSEQ + (size_t)MROWS * HID * 2)     // Sseq = 64MB
#define OFF_CAR (OFF_MIR + (size_t)4 * SBUF * 2)         // 4 mirrors fp16
#define OFF_CNT (OFF_CAR + (size_t)2 * SBUF * 4)         // 2 carries fp32
// flags: 4 stages x 4 waves x 64 cg ints = 4KB

__device__ __forceinline__ half8 ld8(const _Float16* p) {
    return *reinterpret_cast<const half8*>(p);
}

__device__ __forceinline__ half8 cvt8(const float* p) {
    const float4v a = *reinterpret_cast<const float4v*>(p);
    const float4v b = *reinterpret_cast<const float4v*>(p + 4);
    half8 r;
    r[0] = (_Float16)a[0]; r[1] = (_Float16)a[1];
    r[2] = (_Float16)a[2]; r[3] = (_Float16)a[3];
    r[4] = (_Float16)b[0]; r[5] = (_Float16)b[1];
    r[6] = (_Float16)b[2]; r[7] = (_Float16)b[3];
    return r;
}

// ---- prep: transpose+convert weights to fp16 [n][k] ----
// slots per layer l: l*5+0 = w_in[l]^T ; l*5+1..4 = w_h[l][d]^T
__global__ __launch_bounds__(256) void wprep(const float* __restrict__ w_in,
                                             const float* __restrict__ w_h,
                                             _Float16* __restrict__ Wt) {
    const int bid = (int)blockIdx.x;
    const int tk = bid & 31;
    const int tn = (bid >> 5) & 63;
    const int slot = bid >> 11;  // 0..9
    const int l = slot / 5;
    const int j = slot - l * 5;
    const float* __restrict__ src = (j == 0)
        ? (w_in + (size_t)l * WSLOT)
        : (w_h + (size_t)(l * ND + (j - 1)) * WSLOT);
    __shared__ float tile[32][33];
    const int tx = (int)(threadIdx.x & 31u);
    const int ty = (int)(threadIdx.x >> 5);
    const int n = tn * 32 + tx;
#pragma unroll
    for (int r = 0; r < 4; ++r) {
        const int k = tk * 32 + ty + r * 8;
        tile[ty + r * 8][tx] = src[(size_t)k * NH2 + n];
    }
    __syncthreads();
    _Float16* __restrict__ dst = Wt + (size_t)slot * WSLOT;
#pragma unroll
    for (int r = 0; r < 4; ++r) {
        const int nn = tn * 32 + ty + r * 8;
        const int kk = tk * 32 + tx;
        dst[(size_t)nn * HID + kk] = (_Float16)tile[tx][ty + r * 8];
    }
}

// ---- prep: init mirrors (fp16) + carries (fp32) + flags ----
__global__ void sinit2(const float* __restrict__ state, _Float16* __restrict__ mir0,
                       float* __restrict__ car0, _Float16* __restrict__ mir1,
                       float* __restrict__ car1, int* __restrict__ cnts) {
    const int i = (int)(blockIdx.x * 256 + threadIdx.x);
    if (i < SBUF) {
        const float v0 = state[i];
        const float v1 = state[SBUF + i];
        mir0[i] = (_Float16)v0; car0[i] = v0;
        mir1[i] = (_Float16)v1; car1[i] = v1;
    }
    if (i < 1024) cnts[i] = 0;
}

// ---- bulk input-projection GEMM (layer 0 only): C = x @ w_in0, fp16 out ----
template <bool AF16>
__global__ __launch_bounds__(256) void gemm_proj(const void* __restrict__ Av,
                                                 const _Float16* __restrict__ Bslot,
                                                 _Float16* __restrict__ C) {
    const int bid = (int)blockIdx.x;
    const int nt = bid & 31;    // 32 n-tiles of 64
    const int mt = bid >> 5;    // 512 m-tiles of 64
    const int lane = (int)(threadIdx.x & 63u);
    const int wv = (int)(threadIdx.x >> 6);
    const int lr = lane & 15;
    const int kofs = (lane >> 4) * 8;
    const int m = mt * 64 + wv * 16 + lr;
    float4v acc[4];
#pragma unroll
    for (int i = 0; i < 4; ++i) acc[i] = (float4v){0.f, 0.f, 0.f, 0.f};
#pragma unroll 4
    for (int kb = 0; kb < 32; ++kb) {
        half8 a;
        if (AF16) a = ld8((const _Float16*)Av + (size_t)m * HID + kb * 32 + kofs);
        else      a = cvt8((const float*)Av + (size_t)m * HID + kb * 32 + kofs);
#pragma unroll
        for (int ct = 0; ct < 4; ++ct) {
            const int n = nt * 64 + ct * 16 + lr;
            half8 b = ld8(Bslot + (size_t)n * HID + kb * 32 + kofs);
            acc[ct] = __builtin_amdgcn_mfma_f32_16x16x32_f16(a, b, acc[ct], 0, 0, 0);
        }
    }
#pragma unroll
    for (int ct = 0; ct < 4; ++ct) {
#pragma unroll
        for (int i = 0; i < 4; ++i) {
            const int row = mt * 64 + wv * 16 + (lane >> 4) * 4 + i;
            const int col = nt * 64 + ct * 16 + lr;
            const unsigned short mine =
                __builtin_bit_cast(unsigned short, (_Float16)acc[ct][i]);
            const unsigned short oth = (unsigned short)__shfl_xor((int)mine, 1, 64);
            if ((lane & 1) == 0) {
                const uint32_t pk = (uint32_t)mine | ((uint32_t)oth << 16);
                *reinterpret_cast<uint32_t*>(C + (size_t)row * NH2 + col) = pk;
            }
        }
    }
}

// B-fragment from LDS: [layer][tile][kb][lane] half8
#define WFRAG(lyr, tile, kb)                                                     \
    (*reinterpret_cast<const half8*>(                                            \
        lds + ((size_t)((lyr)*4096 + (tile)*2048 + (kb)*64 + lane)) * 8))

// ---- fused two-layer scan: 513 beats x 4 stage-phases, per-wave sync ----
__global__ __launch_bounds__(256) void rhn_fused(
    const _Float16* __restrict__ Wt,
    const float* __restrict__ bias,      // b_h : [NL][ND][NH2]
    const _Float16* __restrict__ hg0,    // [MROWS][NH2] x@w_in0
    _Float16* __restrict__ sseq,         // [SEQ][NB][HID] layer0 outputs fp16
    _Float16* __restrict__ m0a, _Float16* __restrict__ m0b,
    _Float16* __restrict__ m1a, _Float16* __restrict__ m1b,
    float* __restrict__ car0, float* __restrict__ car1,
    int* __restrict__ flags,             // [4][4][64]
    float* __restrict__ outp,            // [SEQ][NB][HID] fp32 (layer1 out)
    float* __restrict__ fout0, float* __restrict__ fout1) {
    extern __shared__ _Float16 lds[];    // [2 layers][2 tiles][32 kb][64][8] =128KB
    const int wg = (int)blockIdx.x;
    const int d = wg >> 6;
    const int cg = wg & 63;
    const int tid = (int)threadIdx.x;
    const int lane = tid & 63;
    const int wv = tid >> 6;             // wave index = batch-row group
    const int m0 = wv * 16;
    const int lr = lane & 15;
    const int kofs = (lane >> 4) * 8;
    const bool isD0 = (d == 0);

    // fill LDS: both layers' weight slices for this (d, cg)
    for (int i = 0; i < 32; ++i) {
        const int flat = i * 256 + tid;       // 0..8191
        const int lyr = flat >> 12;
        const int rem = flat & 4095;
        const int tile = rem >> 11;
        const int kb = (rem >> 6) & 31;
        const int ln = rem & 63;
        const _Float16* __restrict__ slot =
            Wt + (size_t)((lyr ? 6 : 1) + d) * WSLOT;
        const int col = tile * HID + cg * 16 + (ln & 15);
        *reinterpret_cast<half8*>(lds + (size_t)flat * 8) =
            ld8(slot + (size_t)col * HID + kb * 32 + (ln >> 4) * 8);
    }
    __syncthreads();  // one-time: weights ready for all waves

    const int colh = cg * 16 + lr;
    const float bh0 = bias[d * NH2 + colh];
    const float bg0 = bias[d * NH2 + HID + colh];
    const float bh1 = bias[(ND + d) * NH2 + colh];
    const float bg1 = bias[(ND + d) * NH2 + HID + colh];
    const int prev = (d + 3) & 3;
    // per-wave flag lines: [stage][wave][cg]
    const int* __restrict__ pfl = flags + prev * 256 + wv * 64 + lane;
    int* __restrict__ myf = flags + d * 256 + wv * 64 + cg;
    // w_in[1] streamed fragment base (stage 0 only)
    const _Float16* __restrict__ winp =
        Wt + (size_t)5 * WSLOT + (size_t)(cg * 16 + lr) * HID + kofs;
    const size_t WGOFF = (size_t)HID * HID;  // +HID cols in [n][k] layout

    for (int b = 0; b <= SEQ; ++b) {
        const bool doL0 = (b < SEQ);
        const bool doL1 = (b > 0);
        const int t1 = b - 1;

        // hg0 prefetch (stage0/layer0) -- read-only, independent of the wait
        float pre_h[4], pre_g[4];
        if (isD0 && doL0) {
#pragma unroll
            for (int i = 0; i < 4; ++i) {
                const int gr = m0 + (lane >> 4) * 4 + i;
                const size_t hb = (size_t)(b * NB + gr) * NH2 + colh;
                pre_h[i] = (float)hg0[hb];
                pre_g[i] = (float)hg0[hb + HID];
            }
            __asm__ __volatile__("" :: "v"(pre_h[0]), "v"(pre_h[1]), "v"(pre_h[2]),
                                 "v"(pre_h[3]), "v"(pre_g[0]), "v"(pre_g[1]),
                                 "v"(pre_g[2]), "v"(pre_g[3]));
        }

        // per-wave wait: all 64 prev-stage waves (same wv) reached this beat.
        // One coalesced 64-lane agent load + __all; s_sleep(2) backoff.
        const int target = isD0 ? b : b + 1;
        if (target > 0) {
            int v = __hip_atomic_load(pfl, __ATOMIC_RELAXED, __HIP_MEMORY_SCOPE_AGENT);
            while (!__all(v >= target)) {
                __builtin_amdgcn_s_sleep(2);
                v = __hip_atomic_load(pfl, __ATOMIC_RELAXED, __HIP_MEMORY_SCOPE_AGENT);
            }
        }
        // acquire: invalidate stale L1/L2 so mirrors/sseq/carry read fresh
        __builtin_amdgcn_fence(__ATOMIC_ACQUIRE, "agent");

        // early carry loads; latency hides under the GEMMs
        float sold0[4], sold1[4];
        if (doL0) {
#pragma unroll
            for (int i = 0; i < 4; ++i) {
                const int gr = m0 + (lane >> 4) * 4 + i;
                sold0[i] = __hip_atomic_load(car0 + (size_t)gr * HID + colh,
                                             __ATOMIC_RELAXED, __HIP_MEMORY_SCOPE_AGENT);
            }
            __asm__ __volatile__("" :: "v"(sold0[0]), "v"(sold0[1]), "v"(sold0[2]),
                                 "v"(sold0[3]));
        }
        if (doL1) {
#pragma unroll
            for (int i = 0; i < 4; ++i) {
                const int gr = m0 + (lane >> 4) * 4 + i;
                sold1[i] = __hip_atomic_load(car1 + (size_t)gr * HID + colh,
                                             __ATOMIC_RELAXED, __HIP_MEMORY_SCOPE_AGENT);
            }
            __asm__ __volatile__("" :: "v"(sold1[0]), "v"(sold1[1]), "v"(sold1[2]),
                                 "v"(sold1[3]));
        }

        const int gp0 = b * 4 + d;
        const int gp1 = t1 * 4 + d;
        const _Float16* __restrict__ a0p =
            ((gp0 & 1) ? m0b : m0a) + (size_t)(m0 + lr) * HID + kofs;
        const _Float16* __restrict__ a1p =
            ((gp1 & 1) ? m1b : m1a) + (size_t)(m0 + lr) * HID + kofs;
        const _Float16* __restrict__ a2p =
            sseq + ((size_t)t1 * NB + (m0 + lr)) * HID + kofs;

        float4v acch0 = {0.f, 0.f, 0.f, 0.f}, accg0 = {0.f, 0.f, 0.f, 0.f};
        float4v acch1 = {0.f, 0.f, 0.f, 0.f}, accg1 = {0.f, 0.f, 0.f, 0.f};

        if (doL0 && doL1) {
            if (isD0) {
#pragma unroll 4
                for (int kb = 0; kb < 32; ++kb) {
                    half8 a0 = ld8(a0p + kb * 32);
                    half8 a1 = ld8(a1p + kb * 32);
                    half8 a2 = ld8(a2p + kb * 32);
                    acch0 = __builtin_amdgcn_mfma_f32_16x16x32_f16(a0, WFRAG(0, 0, kb), acch0, 0, 0, 0);
                    accg0 = __builtin_amdgcn_mfma_f32_16x16x32_f16(a0, WFRAG(0, 1, kb), accg0, 0, 0, 0);
                    acch1 = __builtin_amdgcn_mfma_f32_16x16x32_f16(a1, WFRAG(1, 0, kb), acch1, 0, 0, 0);
                    accg1 = __builtin_amdgcn_mfma_f32_16x16x32_f16(a1, WFRAG(1, 1, kb), accg1, 0, 0, 0);
                    acch1 = __builtin_amdgcn_mfma_f32_16x16x32_f16(a2, ld8(winp + (size_t)kb * 32), acch1, 0, 0, 0);
                    accg1 = __builtin_amdgcn_mfma_f32_16x16x32_f16(a2, ld8(winp + WGOFF + kb * 32), accg1, 0, 0, 0);
                }
            } else {
#pragma unroll 8
                for (int kb = 0; kb < 32; ++kb) {
                    half8 a0 = ld8(a0p + kb * 32);
                    half8 a1 = ld8(a1p + kb * 32);
                    acch0 = __builtin_amdgcn_mfma_f32_16x16x32_f16(a0, WFRAG(0, 0, kb), acch0, 0, 0, 0);
                    accg0 = __builtin_amdgcn_mfma_f32_16x16x32_f16(a0, WFRAG(0, 1, kb), accg0, 0, 0, 0);
                    acch1 = __builtin_amdgcn_mfma_f32_16x16x32_f16(a1, WFRAG(1, 0, kb), acch1, 0, 0, 0);
                    accg1 = __builtin_amdgcn_mfma_f32_16x16x32_f16(a1, WFRAG(1, 1, kb), accg1, 0, 0, 0);
                }
            }
        } else if (doL0) {  // b == 0
#pragma unroll 8
            for (int kb = 0; kb < 32; ++kb) {
                half8 a0 = ld8(a0p + kb * 32);
                acch0 = __builtin_amdgcn_mfma_f32_16x16x32_f16(a0, WFRAG(0, 0, kb), acch0, 0, 0, 0);
                accg0 = __builtin_amdgcn_mfma_f32_16x16x32_f16(a0, WFRAG(0, 1, kb), accg0, 0, 0, 0);
            }
        } else {  // b == SEQ : layer1 only
            if (isD0) {
#pragma unroll 8
                for (int kb = 0; kb < 32; ++kb) {
                    half8 a1 = ld8(a1p + kb * 32);
                    half8 a2 = ld8(a2p + kb * 32);
                    acch1 = __builtin_amdgcn_mfma_f32_16x16x32_f16(a1, WFRAG(1, 0, kb), acch1, 0, 0, 0);
                    accg1 = __builtin_amdgcn_mfma_f32_16x16x32_f16(a1, WFRAG(1, 1, kb), accg1, 0, 0, 0);
                    acch1 = __builtin_amdgcn_mfma_f32_16x16x32_f16(a2, ld8(winp + (size_t)kb * 32), acch1, 0, 0, 0);
                    accg1 = __builtin_amdgcn_mfma_f32_16x16x32_f16(a2, ld8(winp + WGOFF + kb * 32), accg1, 0, 0, 0);
                }
            } else {
#pragma unroll 8
                for (int kb = 0; kb < 32; ++kb) {
                    half8 a1 = ld8(a1p + kb * 32);
                    acch1 = __builtin_amdgcn_mfma_f32_16x16x32_f16(a1, WFRAG(1, 0, kb), acch1, 0, 0, 0);
                    accg1 = __builtin_amdgcn_mfma_f32_16x16x32_f16(a1, WFRAG(1, 1, kb), accg1, 0, 0, 0);
                }
            }
        }

        float sn0v[4], sn1v[4];
        // ---- epilogue layer 0 (t = b): carry/mirror/sseq (consumed data) ----
        if (doL0) {
            _Float16* __restrict__ mw = ((gp0 + 1) & 1) ? m0b : m0a;
#pragma unroll
            for (int i = 0; i < 4; ++i) {
                const int gr = m0 + (lane >> 4) * 4 + i;
                const size_t idx = (size_t)gr * HID + colh;
                float ah = acch0[i] + bh0;
                float ag = accg0[i] + bg0;
                if (isD0) { ah += pre_h[i]; ag += pre_g[i]; }
                const float hv = 1.0f - __fdividef(2.0f, __expf(2.0f * ah) + 1.0f);
                const float gv = __fdividef(1.0f, 1.0f + __expf(-ag));
                const float sn = hv * gv + sold0[i] * (1.f - gv);
                sn0v[i] = sn;
                __hip_atomic_store(car0 + idx, sn, __ATOMIC_RELAXED,
                                   __HIP_MEMORY_SCOPE_AGENT);
                const unsigned short mine = __builtin_bit_cast(unsigned short, (_Float16)sn);
                const unsigned short oth = (unsigned short)__shfl_xor((int)mine, 1, 64);
                const uint32_t pk = (uint32_t)mine | ((uint32_t)oth << 16);
                if ((lane & 1) == 0) {
                    __hip_atomic_store(reinterpret_cast<uint32_t*>(mw + idx), pk,
                                       __ATOMIC_RELAXED, __HIP_MEMORY_SCOPE_AGENT);
                    if (d == 3) {
                        __hip_atomic_store(
                            reinterpret_cast<uint32_t*>(sseq + (size_t)b * SBUF + idx),
                            pk, __ATOMIC_RELAXED, __HIP_MEMORY_SCOPE_AGENT);
                    }
                }
            }
        }
        // ---- epilogue layer 1 (t = b-1): carry/mirror (consumed data) ----
        if (doL1) {
            _Float16* __restrict__ mw = ((gp1 + 1) & 1) ? m1b : m1a;
#pragma unroll
            for (int i = 0; i < 4; ++i) {
                const int gr = m0 + (lane >> 4) * 4 + i;
                const size_t idx = (size_t)gr * HID + colh;
                const float ah = acch1[i] + bh1;
                const float ag = accg1[i] + bg1;
                const float hv = 1.0f - __fdividef(2.0f, __expf(2.0f * ah) + 1.0f);
                const float gv = __fdividef(1.0f, 1.0f + __expf(-ag));
                const float sn = hv * gv + sold1[i] * (1.f - gv);
                sn1v[i] = sn;
                __hip_atomic_store(car1 + idx, sn, __ATOMIC_RELAXED,
                                   __HIP_MEMORY_SCOPE_AGENT);
                const unsigned short mine = __builtin_bit_cast(unsigned short, (_Float16)sn);
                const unsigned short oth = (unsigned short)__shfl_xor((int)mine, 1, 64);
                const uint32_t pk = (uint32_t)mine | ((uint32_t)oth << 16);
                if ((lane & 1) == 0) {
                    __hip_atomic_store(reinterpret_cast<uint32_t*>(mw + idx), pk,
                                       __ATOMIC_RELAXED, __HIP_MEMORY_SCOPE_AGENT);
                }
            }
        }

        // drain THIS WAVE's stores (MALL-acked), then publish per-wave flag
        __asm__ __volatile__("s_waitcnt vmcnt(0)" ::: "memory");
        if (lane == 0)
            __hip_atomic_store(myf, b + 1, __ATOMIC_RELAXED, __HIP_MEMORY_SCOPE_AGENT);

        // ---- post-flag dead-end outputs (nobody reads these in-kernel):
        // their store-ack overlaps the next poll instead of the chain.
        if (d == 3) {
            if (doL1) {
#pragma unroll
                for (int i = 0; i < 4; ++i) {
                    const int gr = m0 + (lane >> 4) * 4 + i;
                    const size_t idx = (size_t)gr * HID + colh;
                    outp[(size_t)t1 * SBUF + idx] = sn1v[i];
                    if (t1 == SEQ - 1) fout1[idx] = sn1v[i];
                }
            }
            if (doL0 && b == SEQ - 1) {
#pragma unroll
                for (int i = 0; i < 4; ++i) {
                    const int gr = m0 + (lane >> 4) * 4 + i;
                    const size_t idx = (size_t)gr * HID + colh;
                    fout0[idx] = sn0v[i];
                }
            }
        }
    }
}

extern "C" void kernel_launch(void* const* d_in, const int* in_sizes, int n_in,
                              void* d_out, int out_size, void* d_ws, size_t ws_size,
                              hipStream_t stream) {
    (void)in_sizes; (void)n_in; (void)out_size; (void)ws_size;
    const float* x     = (const float*)d_in[0];
    const float* state = (const float*)d_in[1];
    const float* w_in  = (const float*)d_in[2];
    const float* w_h   = (const float*)d_in[3];
    const float* b_h   = (const float*)d_in[4];
    float* out = (float*)d_out;
    char* ws = (char*)d_ws;
    _Float16* Wt   = (_Float16*)ws;
    _Float16* HG0  = (_Float16*)(ws + OFF_HG0);
    _Float16* Sseq = (_Float16*)(ws + OFF_SSEQ);
    _Float16* mir0a = (_Float16*)(ws + OFF_MIR);
    _Float16* mir0b = mir0a + SBUF;
    _Float16* mir1a = mir0b + SBUF;
    _Float16* mir1b = mir1a + SBUF;
    float* car0 = (float*)(ws + OFF_CAR);
    float* car1 = car0 + SBUF;
    int* flags = (int*)(ws + OFF_CNT);

    (void)hipFuncSetAttribute((const void*)rhn_fused,
                              hipFuncAttributeMaxDynamicSharedMemorySize, 131072);

    wprep<<<10 * 64 * 32, 256, 0, stream>>>(w_in, w_h, Wt);
    sinit2<<<(SBUF + 255) / 256, 256, 0, stream>>>(state, mir0a, car0, mir1a, car1, flags);
    // HG0 = x @ w_in[0]
    gemm_proj<false><<<512 * 32, 256, 0, stream>>>((const void*)x, Wt + 0 * WSLOT, HG0);
    // fused two-layer pipelined scan (per-wave sync)
    rhn_fused<<<256, 256, 131072, stream>>>(
        Wt, b_h, HG0, Sseq, mir0a, mir0b, mir1a, mir1b, car0, car1, flags,
        out, out + (size_t)SEQ * SBUF, out + (size_t)SEQ * SBUF + SBUF);
}